// Round 6
// baseline (302.945 us; speedup 1.0000x reference)
//
#include <hip/hip_runtime.h>

// BilinearMixture. R5 finding: bound by L2 128B-line fill COUNT (~2.7M fills
// @3.7TB/s): int8 64B rows didn't reduce FETCH vs fp16 128B rows. R6: bucket
// edges by u into 512 bins (3 streaming passes) -> per-block u working set
// ~12.5KB (hot), and the 3.2MB int8 v-table becomes L2-resident per XCD.
// Main kernel keeps R5's proven body: 16 lanes/edge, int8 rows + per-row
// scale, 2-edge ILP, K=3 DPP reduction, scalars post-reduction.

#define NBINS   512
#define NBLK_HS 256

template <int CTRL>
__device__ __forceinline__ float dpp_add(float x) {
    int t = __builtin_amdgcn_update_dpp(0, __float_as_int(x), CTRL, 0xF, 0xF, true);
    return x + __int_as_float(t);
}
template <int CTRL>
__device__ __forceinline__ float dpp_max(float x) {
    int t = __builtin_amdgcn_update_dpp(0, __float_as_int(x), CTRL, 0xF, 0xF, true);
    return fmaxf(x, __int_as_float(t));
}
__device__ __forceinline__ void reduce16_3(float& a, float& b, float& c) {
    a = dpp_add<0xB1>(a);  b = dpp_add<0xB1>(b);  c = dpp_add<0xB1>(c);
    a = dpp_add<0x4E>(a);  b = dpp_add<0x4E>(b);  c = dpp_add<0x4E>(c);
    a = dpp_add<0x124>(a); b = dpp_add<0x124>(b); c = dpp_add<0x124>(c);
    a = dpp_add<0x128>(a); b = dpp_add<0x128>(b); c = dpp_add<0x128>(c);
}
__device__ __forceinline__ float reduce16_max(float x) {
    x = dpp_max<0xB1>(x); x = dpp_max<0x4E>(x);
    x = dpp_max<0x124>(x); x = dpp_max<0x128>(x);
    return x;
}

// ---------- quantization: fp32 rows -> int8 (dword/lane) + per-row scale ---
__global__ __launch_bounds__(256) void quantize_tables_i8(
    const float* __restrict__ u_feat, const float* __restrict__ v_feat,
    int* __restrict__ u_q, int* __restrict__ v_q,
    float* __restrict__ u_s, float* __restrict__ v_s,
    int nrow_u, int nrow_v)
{
    const int tid   = blockIdx.x * blockDim.x + threadIdx.x;
    const int sl    = threadIdx.x & 15;
    const int group = tid >> 4;
    const int ng    = (gridDim.x * blockDim.x) >> 4;
    const int ntot  = nrow_u + nrow_v;

    for (int r = group; r < ntot; r += ng) {
        const bool  isU = (r < nrow_u);
        const int   rr  = isU ? r : r - nrow_u;
        const float* src = (isU ? u_feat : v_feat) + (size_t)rr * 64 + sl * 4;
        const float4 x = *reinterpret_cast<const float4*>(src);

        float am = fmaxf(fmaxf(fabsf(x.x), fabsf(x.y)),
                         fmaxf(fabsf(x.z), fabsf(x.w)));
        am = reduce16_max(am);
        am = fmaxf(am, 1e-20f);
        const float inv   = 127.0f / am;
        const float scale = am / 127.0f;

        const int b0 = (int)rintf(x.x * inv);
        const int b1 = (int)rintf(x.y * inv);
        const int b2 = (int)rintf(x.z * inv);
        const int b3 = (int)rintf(x.w * inv);
        const int packed = (b0 & 255) | ((b1 & 255) << 8) |
                           ((b2 & 255) << 16) | ((b3 & 255) << 24);

        (isU ? u_q : v_q)[(size_t)rr * 16 + sl] = packed;
        if (sl == 0) (isU ? u_s : v_s)[rr] = scale;
    }
}

// ---------- pass H: per-block 512-bin histogram of u ----------
__global__ __launch_bounds__(256) void edge_hist(
    const int* __restrict__ u_idx, int E, float binScale,
    int* __restrict__ hist /* [NBLK_HS][NBINS] */)
{
    __shared__ int h[NBINS];
    for (int i = threadIdx.x; i < NBINS; i += 256) h[i] = 0;
    __syncthreads();
    const int chunk = (E + NBLK_HS - 1) / NBLK_HS;
    const int s = blockIdx.x * chunk;
    const int e = min(E, s + chunk);
    for (int i = s + threadIdx.x; i < e; i += 256) {
        int b = min(NBINS - 1, (int)((float)u_idx[i] * binScale));
        atomicAdd(&h[b], 1);
    }
    __syncthreads();
    for (int i = threadIdx.x; i < NBINS; i += 256)
        hist[blockIdx.x * NBINS + i] = h[i];
}

// ---------- pass P: bin starts + per-block offsets ----------
__global__ __launch_bounds__(256) void edge_prefix(
    const int* __restrict__ hist, int* __restrict__ off,
    int* __restrict__ binStart, int E)
{
    __shared__ int tot[NBINS];
    __shared__ int start[NBINS + 1];
    for (int b = threadIdx.x; b < NBINS; b += 256) {
        int t = 0;
        #pragma unroll 8
        for (int k = 0; k < NBLK_HS; ++k) t += hist[k * NBINS + b];
        tot[b] = t;
    }
    __syncthreads();
    if (threadIdx.x == 0) {
        int acc = 0;
        for (int b = 0; b < NBINS; ++b) { start[b] = acc; acc += tot[b]; }
        start[NBINS] = acc;   // == E
    }
    __syncthreads();
    for (int b = threadIdx.x; b < NBINS; b += 256) {
        int acc = start[b];
        for (int k = 0; k < NBLK_HS; ++k) {
            off[k * NBINS + b] = acc;
            acc += hist[k * NBINS + b];
        }
    }
    for (int b = threadIdx.x; b <= NBINS; b += 256) binStart[b] = start[b];
}

// ---------- pass S: scatter (u,v) + edge id into binned order ----------
__global__ __launch_bounds__(256) void edge_scatter(
    const int* __restrict__ u_idx, const int* __restrict__ v_idx,
    int E, float binScale, const int* __restrict__ off,
    int2* __restrict__ buv, int* __restrict__ bedge)
{
    __shared__ int cur[NBINS];
    for (int i = threadIdx.x; i < NBINS; i += 256)
        cur[i] = off[blockIdx.x * NBINS + i];
    __syncthreads();
    const int chunk = (E + NBLK_HS - 1) / NBLK_HS;
    const int s = blockIdx.x * chunk;
    const int e = min(E, s + chunk);
    for (int i = s + threadIdx.x; i < e; i += 256) {
        const int u = u_idx[i];
        const int v = v_idx[i];
        const int b = min(NBINS - 1, (int)((float)u * binScale));
        const int p = atomicAdd(&cur[b], 1);
        buv[p]   = make_int2(u, v);
        bedge[p] = i;
    }
}

// ---------- main: binned edges, int8 gathers, fp32 math ----------
__global__ __launch_bounds__(256) void bilinear_binned_i8(
    const int* __restrict__ u_q, const int* __restrict__ v_q,
    const float* __restrict__ u_s, const float* __restrict__ v_s,
    const float* __restrict__ W, const float* __restrict__ scalars,
    const float* __restrict__ u_bias, const float* __restrict__ v_bias,
    const int2* __restrict__ buv, const int* __restrict__ bedge,
    const int* __restrict__ binStart, float* __restrict__ out)
{
    const int sl = threadIdx.x & 15;
    const int g  = threadIdx.x >> 4;              // group in block (0..15)

    // Block -> (bin, quarter). Assumes blockIdx%8 ~ XCD (perf-only heuristic;
    // bucket-locality + v-residency hold even if the mapping is wrong).
    const int B   = blockIdx.x;
    const int xcd = B & 7;
    const int j   = B >> 3;                        // 0..255
    const int bin = xcd + 8 * (j >> 2);            // 0..511
    const int sub = j & 3;
    const int bs  = binStart[bin];
    const int be  = binStart[bin + 1];
    const int cnt = be - bs;
    const int q   = (cnt + 3) >> 2;
    const int cs  = bs + sub * q;
    const int ce  = min(be, cs + q);
    if (cs >= ce) return;

    // Per-lane W slice + writer-lane scalars.
    const int d0 = sl * 4;
    float w0[4], w1[4], w2[4];
    #pragma unroll
    for (int t = 0; t < 4; ++t) {
        w0[t] = W[0 * 64 + d0 + t];
        w1[t] = W[1 * 64 + d0 + t];
        w2[t] = W[2 * 64 + d0 + t];
    }
    float s0 = 0.f, s1 = 0.f, s2 = 0.f;
    if (sl < 5) { s0 = scalars[0 * 5 + sl]; s1 = scalars[1 * 5 + sl]; s2 = scalars[2 * 5 + sl]; }

    // 16 groups x 2 edges per iteration.
    for (int p0 = cs + g * 2; p0 < ce; p0 += 32) {
        const int  p1   = p0 + 1;
        const bool has1 = (p1 < ce);

        const int2 uv0 = buv[p0];
        const int2 uv1 = has1 ? buv[p1] : uv0;
        const int  e0  = bedge[p0];
        const int  e1  = has1 ? bedge[p1] : e0;

        // Row gathers: one dword/lane, 4 rows in flight.
        const int qu0 = u_q[(size_t)uv0.x * 16 + sl];
        const int qv0 = v_q[(size_t)uv0.y * 16 + sl];
        const int qu1 = u_q[(size_t)uv1.x * 16 + sl];
        const int qv1 = v_q[(size_t)uv1.y * 16 + sl];

        float ub0 = 0.f, vb0 = 0.f, ub1 = 0.f, vb1 = 0.f;
        float ss0 = 0.f, ss1 = 0.f;
        if (sl < 5) {
            ss0 = u_s[uv0.x] * v_s[uv0.y];
            ss1 = u_s[uv1.x] * v_s[uv1.y];
            ub0 = u_bias[(size_t)uv0.x * 5 + sl];
            vb0 = v_bias[(size_t)uv0.y * 5 + sl];
            ub1 = u_bias[(size_t)uv1.x * 5 + sl];
            vb1 = v_bias[(size_t)uv1.y * 5 + sl];
        }

        float ua0 = (float)((qu0 << 24) >> 24), ua1 = (float)((qu0 << 16) >> 24),
              ua2 = (float)((qu0 <<  8) >> 24), ua3 = (float)( qu0        >> 24);
        float va0 = (float)((qv0 << 24) >> 24), va1 = (float)((qv0 << 16) >> 24),
              va2 = (float)((qv0 <<  8) >> 24), va3 = (float)( qv0        >> 24);
        float xb0 = (float)((qu1 << 24) >> 24), xb1 = (float)((qu1 << 16) >> 24),
              xb2 = (float)((qu1 <<  8) >> 24), xb3 = (float)( qu1        >> 24);
        float yb0 = (float)((qv1 << 24) >> 24), yb1 = (float)((qv1 << 16) >> 24),
              yb2 = (float)((qv1 <<  8) >> 24), yb3 = (float)( qv1        >> 24);

        const float a0 = ua0 * va0, a1 = ua1 * va1, a2 = ua2 * va2, a3 = ua3 * va3;
        const float b0 = xb0 * yb0, b1 = xb1 * yb1, b2 = xb2 * yb2, b3 = xb3 * yb3;

        float qa0 = a0*w0[0] + a1*w0[1] + a2*w0[2] + a3*w0[3];
        float qa1 = a0*w1[0] + a1*w1[1] + a2*w1[2] + a3*w1[3];
        float qa2 = a0*w2[0] + a1*w2[1] + a2*w2[2] + a3*w2[3];
        float qb0 = b0*w0[0] + b1*w0[1] + b2*w0[2] + b3*w0[3];
        float qb1 = b0*w1[0] + b1*w1[1] + b2*w1[2] + b3*w1[3];
        float qb2 = b0*w2[0] + b1*w2[1] + b2*w2[2] + b3*w2[3];

        reduce16_3(qa0, qa1, qa2);
        reduce16_3(qb0, qb1, qb2);

        if (sl < 5) {
            out[(size_t)e0 * 5 + sl] = (qa0 * s0 + qa1 * s1 + qa2 * s2) * ss0 + ub0 + vb0;
            if (has1)
                out[(size_t)e1 * 5 + sl] = (qb0 * s0 + qb1 * s1 + qb2 * s2) * ss1 + ub1 + vb1;
        }
    }
}

// ---------- fallback: direct fp32 (only if ws too small) ----------
__global__ __launch_bounds__(256) void bilinear_edges_f32(
    const float* __restrict__ u_feat, const float* __restrict__ v_feat,
    const float* __restrict__ W, const float* __restrict__ scalars,
    const float* __restrict__ u_bias, const float* __restrict__ v_bias,
    const int* __restrict__ u_idx, const int* __restrict__ v_idx,
    float* __restrict__ out, int E)
{
    const int tid    = blockIdx.x * blockDim.x + threadIdx.x;
    const int sl     = threadIdx.x & 15;
    const int group  = tid >> 4;
    const int ngroup = (gridDim.x * blockDim.x) >> 4;

    const int d0 = sl * 4;
    float w0[4], w1[4], w2[4];
    #pragma unroll
    for (int t = 0; t < 4; ++t) {
        w0[t] = W[0 * 64 + d0 + t];
        w1[t] = W[1 * 64 + d0 + t];
        w2[t] = W[2 * 64 + d0 + t];
    }
    float s0 = 0.f, s1 = 0.f, s2 = 0.f;
    if (sl < 5) { s0 = scalars[0 * 5 + sl]; s1 = scalars[1 * 5 + sl]; s2 = scalars[2 * 5 + sl]; }

    for (int e = group; e < E; e += ngroup) {
        const int uu = u_idx[e];
        const int vv = v_idx[e];
        const float4 u4 = *reinterpret_cast<const float4*>(u_feat + (size_t)uu * 64 + d0);
        const float4 v4 = *reinterpret_cast<const float4*>(v_feat + (size_t)vv * 64 + d0);
        float ub = 0.f, vb = 0.f;
        if (sl < 5) { ub = u_bias[(size_t)uu * 5 + sl]; vb = v_bias[(size_t)vv * 5 + sl]; }

        const float p0 = u4.x * v4.x, p1 = u4.y * v4.y,
                    p2 = u4.z * v4.z, p3 = u4.w * v4.w;
        float q0 = p0*w0[0] + p1*w0[1] + p2*w0[2] + p3*w0[3];
        float q1 = p0*w1[0] + p1*w1[1] + p2*w1[2] + p3*w1[3];
        float q2 = p0*w2[0] + p1*w2[1] + p2*w2[2] + p3*w2[3];
        reduce16_3(q0, q1, q2);
        if (sl < 5)
            out[(size_t)e * 5 + sl] = q0 * s0 + q1 * s1 + q2 * s2 + ub + vb;
    }
}

extern "C" void kernel_launch(void* const* d_in, const int* in_sizes, int n_in,
                              void* d_out, int out_size, void* d_ws, size_t ws_size,
                              hipStream_t stream) {
    const float* u_feat  = (const float*)d_in[0];
    const float* v_feat  = (const float*)d_in[1];
    const float* W       = (const float*)d_in[2];
    const float* scalars = (const float*)d_in[3];
    const float* u_bias  = (const float*)d_in[4];
    const float* v_bias  = (const float*)d_in[5];
    const int*   u_idx   = (const int*)d_in[6];
    const int*   v_idx   = (const int*)d_in[7];
    float*       out     = (float*)d_out;

    const int nu = in_sizes[0];          // NUM_USERS * 64
    const int nv = in_sizes[1];          // NUM_ITEMS * 64
    const int E  = in_sizes[6];          // 2,000,000 edges
    const int nrow_u = nu / 64;
    const int nrow_v = nv / 64;

    // Workspace layout (all 4B-aligned; buv first for 8B alignment):
    //   buv[E] int2 | u_q | v_q | u_s | v_s | bedge[E] | hist | off | binStart
    const size_t need =
        (size_t)E * 8 +
        (size_t)(nrow_u + nrow_v) * 16 * 4 +
        (size_t)(nrow_u + nrow_v) * 4 +
        (size_t)E * 4 +
        (size_t)2 * NBLK_HS * NBINS * 4 +
        (size_t)(NBINS + 1) * 4;

    if (ws_size >= need) {
        int2* buv      = (int2*)d_ws;
        int*  u_q      = (int*)(buv + E);
        int*  v_q      = u_q + (size_t)nrow_u * 16;
        float* u_s     = (float*)(v_q + (size_t)nrow_v * 16);
        float* v_s     = u_s + nrow_u;
        int*  bedge    = (int*)(v_s + nrow_v);
        int*  hist     = bedge + E;
        int*  off      = hist + (size_t)NBLK_HS * NBINS;
        int*  binStart = off + (size_t)NBLK_HS * NBINS;

        const float binScale = (float)NBINS / (float)nrow_u;

        quantize_tables_i8<<<2048, 256, 0, stream>>>(
            u_feat, v_feat, u_q, v_q, u_s, v_s, nrow_u, nrow_v);
        edge_hist<<<NBLK_HS, 256, 0, stream>>>(u_idx, E, binScale, hist);
        edge_prefix<<<1, 256, 0, stream>>>(hist, off, binStart, E);
        edge_scatter<<<NBLK_HS, 256, 0, stream>>>(
            u_idx, v_idx, E, binScale, off, buv, bedge);
        bilinear_binned_i8<<<2048, 256, 0, stream>>>(
            u_q, v_q, u_s, v_s, W, scalars, u_bias, v_bias,
            buv, bedge, binStart, out);
    } else {
        bilinear_edges_f32<<<2048, 256, 0, stream>>>(
            u_feat, v_feat, W, scalars, u_bias, v_bias, u_idx, v_idx, out, E);
    }
}

// Round 8
// 261.912 us; speedup vs baseline: 1.1567x; 1.1567x over previous
//
#include <hip/hip_runtime.h>
#include <hip/hip_fp16.h>

// BilinearMixture via MFMA. R4/R5/R6 all ~106us with FETCH 345/345/179 MB and
// VALU ~49% -> time invariant to bytes & locality => instruction-structure
// bound (~33 CU-cy/edge). R7: out[tile16,5] = P[16x64] @ M[64x5] with
// mfma_f32_16x16x32_f16 x2 (K=64). Unpack+partials+DPP-reduce (~640 lane-ops
// /edge) collapse into 8 v_pk_mul_f16 + 2 MFMA per 16 edges. k-slot mapping
// cancels between A and B (we fill both); C/D layout is the HW-verified
// col=lane&15, row=(lane>>4)*4+reg. fp16 tables (bytes don't matter; no
// scale gathers), natural edge order, no binning.

typedef _Float16 f16x8 __attribute__((ext_vector_type(8)));
typedef float    f32x4 __attribute__((ext_vector_type(4)));

// ---------- conversion: fp32 tables -> fp16 in workspace (proven ~free) ----
__global__ __launch_bounds__(256) void convert_tables_fp16(
    const float* __restrict__ u_feat, const float* __restrict__ v_feat,
    __half* __restrict__ u_h, __half* __restrict__ v_h, int nu, int nv)
{
    const int tid  = blockIdx.x * blockDim.x + threadIdx.x;
    const int nthr = gridDim.x * blockDim.x;
    for (int i = tid * 4; i < nu; i += nthr * 4) {
        const float4 x = *reinterpret_cast<const float4*>(u_feat + i);
        *reinterpret_cast<__half2*>(u_h + i)     = __floats2half2_rn(x.x, x.y);
        *reinterpret_cast<__half2*>(u_h + i + 2) = __floats2half2_rn(x.z, x.w);
    }
    for (int i = tid * 4; i < nv; i += nthr * 4) {
        const float4 x = *reinterpret_cast<const float4*>(v_feat + i);
        *reinterpret_cast<__half2*>(v_h + i)     = __floats2half2_rn(x.x, x.y);
        *reinterpret_cast<__half2*>(v_h + i + 2) = __floats2half2_rn(x.z, x.w);
    }
}

// ---------- main: one 16-edge tile per wave-iteration, 2 MFMAs ----------
__global__ __launch_bounds__(256) void bilinear_mfma(
    const __half* __restrict__ u_h, const __half* __restrict__ v_h,
    const float* __restrict__ W, const float* __restrict__ scalars,
    const float* __restrict__ u_bias, const float* __restrict__ v_bias,
    const int* __restrict__ u_idx, const int* __restrict__ v_idx,
    float* __restrict__ out, int E, int ntiles)
{
    const int lane = threadIdx.x & 63;
    const int r    = lane & 15;   // A-row (edge in tile) / B-col / C-col
    const int h    = lane >> 4;   // k-group (owns 8 of 32 k-slots per MFMA)
    const int w    = blockIdx.x * (blockDim.x >> 6) + (threadIdx.x >> 6);
    const int nw   = gridDim.x * (blockDim.x >> 6);

    // B fragments: M[d][c] = sum_k W[k][d]*scalars[k][c], col c=r (0 for r>=5),
    // k-slot (h,j) <- logical d = h*8+j (MFMA1) / 32+h*8+j (MFMA2). One-time.
    float sc0 = 0.f, sc1 = 0.f, sc2 = 0.f;
    if (r < 5) { sc0 = scalars[r]; sc1 = scalars[5 + r]; sc2 = scalars[10 + r]; }
    f16x8 B0, B1;
    #pragma unroll
    for (int j = 0; j < 8; ++j) {
        const int d0 = h * 8 + j;
        const int d1 = 32 + d0;
        B0[j] = (_Float16)(W[d0] * sc0 + W[64 + d0] * sc1 + W[128 + d0] * sc2);
        B1[j] = (_Float16)(W[d1] * sc0 + W[64 + d1] * sc1 + W[128 + d1] * sc2);
    }

    for (int t = w; t < ntiles; t += nw) {
        const int e0 = t * 16;
        const int er = min(e0 + r, E - 1);
        const int ua = u_idx[er];
        const int va = v_idx[er];

        // A-source gathers: 16B per lane, row = 128B = one line per edge-row.
        const __half* up = u_h + (size_t)ua * 64 + h * 8;
        const __half* vp = v_h + (size_t)va * 64 + h * 8;
        const f16x8 au0 = *reinterpret_cast<const f16x8*>(up);
        const f16x8 au1 = *reinterpret_cast<const f16x8*>(up + 32);
        const f16x8 av0 = *reinterpret_cast<const f16x8*>(vp);
        const f16x8 av1 = *reinterpret_cast<const f16x8*>(vp + 32);

        // P fragments: elementwise fp16 product (v_pk_mul_f16 x4 each).
        const f16x8 A0 = au0 * av0;
        const f16x8 A1 = au1 * av1;

        f32x4 acc = {0.f, 0.f, 0.f, 0.f};
        acc = __builtin_amdgcn_mfma_f32_16x16x32_f16(A0, B0, acc, 0, 0, 0);
        acc = __builtin_amdgcn_mfma_f32_16x16x32_f16(A1, B1, acc, 0, 0, 0);

        // Epilogue: C col=r, row=h*4+i. Writer lanes (r<5) add gathered biases.
        #pragma unroll
        for (int i = 0; i < 4; ++i) {
            const int e = e0 + h * 4 + i;
            if (r < 5 && e < E) {
                const int ui = u_idx[e];   // L1-hit (same lines as tile idx)
                const int vi = v_idx[e];
                out[(size_t)e * 5 + r] =
                    acc[i] + u_bias[(size_t)ui * 5 + r] + v_bias[(size_t)vi * 5 + r];
            }
        }
    }
}

// ---------- fallback: direct fp32 (only if ws too small; normally unused) ---
template <int CTRL>
__device__ __forceinline__ float dpp_add(float x) {
    int t = __builtin_amdgcn_update_dpp(0, __float_as_int(x), CTRL, 0xF, 0xF, true);
    return x + __int_as_float(t);
}
__device__ __forceinline__ void reduce16_3(float& a, float& b, float& c) {
    a = dpp_add<0xB1>(a);  b = dpp_add<0xB1>(b);  c = dpp_add<0xB1>(c);
    a = dpp_add<0x4E>(a);  b = dpp_add<0x4E>(b);  c = dpp_add<0x4E>(c);
    a = dpp_add<0x124>(a); b = dpp_add<0x124>(b); c = dpp_add<0x124>(c);
    a = dpp_add<0x128>(a); b = dpp_add<0x128>(b); c = dpp_add<0x128>(c);
}

__global__ __launch_bounds__(256) void bilinear_edges_f32(
    const float* __restrict__ u_feat, const float* __restrict__ v_feat,
    const float* __restrict__ W, const float* __restrict__ scalars,
    const float* __restrict__ u_bias, const float* __restrict__ v_bias,
    const int* __restrict__ u_idx, const int* __restrict__ v_idx,
    float* __restrict__ out, int E)
{
    const int tid    = blockIdx.x * blockDim.x + threadIdx.x;
    const int sl     = threadIdx.x & 15;
    const int group  = tid >> 4;
    const int ngroup = (gridDim.x * blockDim.x) >> 4;

    const int d0 = sl * 4;
    float w0[4], w1[4], w2[4];
    #pragma unroll
    for (int t = 0; t < 4; ++t) {
        w0[t] = W[0 * 64 + d0 + t];
        w1[t] = W[1 * 64 + d0 + t];
        w2[t] = W[2 * 64 + d0 + t];
    }
    float s0 = 0.f, s1 = 0.f, s2 = 0.f;
    if (sl < 5) { s0 = scalars[sl]; s1 = scalars[5 + sl]; s2 = scalars[10 + sl]; }

    for (int e = group; e < E; e += ngroup) {
        const int uu = u_idx[e];
        const int vv = v_idx[e];
        const float4 u4 = *reinterpret_cast<const float4*>(u_feat + (size_t)uu * 64 + d0);
        const float4 v4 = *reinterpret_cast<const float4*>(v_feat + (size_t)vv * 64 + d0);
        float ub = 0.f, vb = 0.f;
        if (sl < 5) { ub = u_bias[(size_t)uu * 5 + sl]; vb = v_bias[(size_t)vv * 5 + sl]; }

        const float p0 = u4.x * v4.x, p1 = u4.y * v4.y,
                    p2 = u4.z * v4.z, p3 = u4.w * v4.w;
        float q0 = p0*w0[0] + p1*w0[1] + p2*w0[2] + p3*w0[3];
        float q1 = p0*w1[0] + p1*w1[1] + p2*w1[2] + p3*w1[3];
        float q2 = p0*w2[0] + p1*w2[1] + p2*w2[2] + p3*w2[3];
        reduce16_3(q0, q1, q2);
        if (sl < 5)
            out[(size_t)e * 5 + sl] = q0 * s0 + q1 * s1 + q2 * s2 + ub + vb;
    }
}

extern "C" void kernel_launch(void* const* d_in, const int* in_sizes, int n_in,
                              void* d_out, int out_size, void* d_ws, size_t ws_size,
                              hipStream_t stream) {
    const float* u_feat  = (const float*)d_in[0];
    const float* v_feat  = (const float*)d_in[1];
    const float* W       = (const float*)d_in[2];
    const float* scalars = (const float*)d_in[3];
    const float* u_bias  = (const float*)d_in[4];
    const float* v_bias  = (const float*)d_in[5];
    const int*   u_idx   = (const int*)d_in[6];
    const int*   v_idx   = (const int*)d_in[7];
    float*       out     = (float*)d_out;

    const int nu = in_sizes[0];          // NUM_USERS * 64
    const int nv = in_sizes[1];          // NUM_ITEMS * 64
    const int E  = in_sizes[6];          // 2,000,000 edges

    const size_t ws_need = (size_t)(nu + nv) * sizeof(__half);

    if (ws_size >= ws_need) {
        __half* u_h = (__half*)d_ws;
        __half* v_h = u_h + nu;
        const int ntiles = (E + 15) / 16;
        convert_tables_fp16<<<2048, 256, 0, stream>>>(u_feat, v_feat, u_h, v_h, nu, nv);
        bilinear_mfma<<<2048, 256, 0, stream>>>(
            u_h, v_h, W, scalars, u_bias, v_bias, u_idx, v_idx, out, E, ntiles);
    } else {
        bilinear_edges_f32<<<2048, 256, 0, stream>>>(
            u_feat, v_feat, W, scalars, u_bias, v_bias, u_idx, v_idx, out, E);
    }
}

// Round 9
// 205.677 us; speedup vs baseline: 1.4729x; 1.2734x over previous
//
#include <hip/hip_runtime.h>
#include <hip/hip_fp16.h>

// BilinearMixture. R7 lesson: MFMA version (fewest instructions) REGRESSED to
// 172us with every pipe idle -> the wall is latency coverage (MLP), not
// instruction count, bytes (R5), or fills (R6). R8: keep the proven gather
// shape (row = one 128B line) but 8 lanes/edge: one f16x8 (16B) load per lane
// covers the row, so each gather instruction touches 8 rows (2x R4's 4);
// products v_pk_mul_f16; K=3 partials via chained v_dot2_f32_f16 (f32 acc);
// 8-lane reduce = 3 DPP steps (xor1, xor2, row_half_mirror). Two 8-edge
// rounds per iteration -> 16 edges, 32 row-lines in flight per wave at ~half
// the wave-instructions/edge of R4.

typedef _Float16 f16x8 __attribute__((ext_vector_type(8)));
typedef _Float16 h2    __attribute__((ext_vector_type(2)));

union F16x8 { f16x8 v; h2 h[4]; };

template <int CTRL>
__device__ __forceinline__ float dpp_add(float x) {
    int t = __builtin_amdgcn_update_dpp(0, __float_as_int(x), CTRL, 0xF, 0xF, true);
    return x + __int_as_float(t);
}
// Sum (a,b,c) across each 8-lane group: xor1 (quad_perm 0xB1), xor2 (0x4E),
// then ROW_HALF_MIRROR (0x141) folds the two quads of each half-row.
__device__ __forceinline__ void reduce8_3(float& a, float& b, float& c) {
    a = dpp_add<0xB1>(a);  b = dpp_add<0xB1>(b);  c = dpp_add<0xB1>(c);
    a = dpp_add<0x4E>(a);  b = dpp_add<0x4E>(b);  c = dpp_add<0x4E>(c);
    a = dpp_add<0x141>(a); b = dpp_add<0x141>(b); c = dpp_add<0x141>(c);
}

__device__ __forceinline__ float dot2acc(h2 a, h2 b, float c) {
#if __has_builtin(__builtin_amdgcn_fdot2)
    return __builtin_amdgcn_fdot2(a, b, c, false);
#else
    return c + (float)a[0] * (float)b[0] + (float)a[1] * (float)b[1];
#endif
}

// ---------- conversion: fp32 tables -> fp16 in workspace (proven ~free) ----
__global__ __launch_bounds__(256) void convert_tables_fp16(
    const float* __restrict__ u_feat, const float* __restrict__ v_feat,
    __half* __restrict__ u_h, __half* __restrict__ v_h, int nu, int nv)
{
    const int tid  = blockIdx.x * blockDim.x + threadIdx.x;
    const int nthr = gridDim.x * blockDim.x;
    for (int i = tid * 4; i < nu; i += nthr * 4) {
        const float4 x = *reinterpret_cast<const float4*>(u_feat + i);
        *reinterpret_cast<__half2*>(u_h + i)     = __floats2half2_rn(x.x, x.y);
        *reinterpret_cast<__half2*>(u_h + i + 2) = __floats2half2_rn(x.z, x.w);
    }
    for (int i = tid * 4; i < nv; i += nthr * 4) {
        const float4 x = *reinterpret_cast<const float4*>(v_feat + i);
        *reinterpret_cast<__half2*>(v_h + i)     = __floats2half2_rn(x.x, x.y);
        *reinterpret_cast<__half2*>(v_h + i + 2) = __floats2half2_rn(x.z, x.w);
    }
}

// ---------- main: 8 lanes/edge, 2 rounds (16 edges) per wave-iteration -----
__global__ __launch_bounds__(256) void bilinear_dot8(
    const __half* __restrict__ u_h, const __half* __restrict__ v_h,
    const float* __restrict__ W, const float* __restrict__ scalars,
    const float* __restrict__ u_bias, const float* __restrict__ v_bias,
    const int* __restrict__ u_idx, const int* __restrict__ v_idx,
    float* __restrict__ out, int E)
{
    const int lane = threadIdx.x & 63;
    const int sl   = lane & 7;                      // lane in 8-group
    const int sg   = lane >> 3;                     // subgroup (edge slot) 0..7
    const int wid  = (blockIdx.x * blockDim.x + threadIdx.x) >> 6;
    const int nw   = (gridDim.x * blockDim.x) >> 6;

    // Lane's W slice, packed fp16: wk[k][j2] covers d = sl*8 + 2*j2 (+1).
    const int d0 = sl * 8;
    h2 wk[3][4];
    #pragma unroll
    for (int k = 0; k < 3; ++k)
        #pragma unroll
        for (int j = 0; j < 4; ++j) {
            wk[k][j][0] = (_Float16)W[k * 64 + d0 + 2 * j];
            wk[k][j][1] = (_Float16)W[k * 64 + d0 + 2 * j + 1];
        }
    float s0 = 0.f, s1 = 0.f, s2 = 0.f;
    if (sl < 5) { s0 = scalars[sl]; s1 = scalars[5 + sl]; s2 = scalars[10 + sl]; }

    const int step = nw * 16;
    int base = wid * 16;
    if (base >= E) return;

    // Prologue indices for both rounds; loop prefetches the next iteration's.
    int ea = base + sg, eb = base + 8 + sg;
    int ua = u_idx[min(ea, E - 1)], va = v_idx[min(ea, E - 1)];
    int ub = u_idx[min(eb, E - 1)], vb = v_idx[min(eb, E - 1)];

    for (; base < E; base += step) {
        const int cea = base + sg, ceb = base + 8 + sg;
        const int cua = ua, cva = va, cub = ub, cvb = vb;

        // Row gathers: 16B/lane; each instruction touches 8 distinct lines.
        F16x8 Ua, Va, Ub, Vb;
        Ua.v = *reinterpret_cast<const f16x8*>(u_h + (size_t)cua * 64 + d0);
        Va.v = *reinterpret_cast<const f16x8*>(v_h + (size_t)cva * 64 + d0);
        Ub.v = *reinterpret_cast<const f16x8*>(u_h + (size_t)cub * 64 + d0);
        Vb.v = *reinterpret_cast<const f16x8*>(v_h + (size_t)cvb * 64 + d0);

        // Prefetch next iteration's indices (breaks idx->gather chain).
        const int nb = base + step;
        if (nb < E) {
            const int nea = nb + sg, neb = nb + 8 + sg;
            ua = u_idx[min(nea, E - 1)]; va = v_idx[min(nea, E - 1)];
            ub = u_idx[min(neb, E - 1)]; vb = v_idx[min(neb, E - 1)];
        }

        // Bias gathers early (writer lanes only); hide under dot/reduce.
        float bua = 0.f, bva = 0.f, bub = 0.f, bvb = 0.f;
        if (sl < 5) {
            bua = u_bias[(size_t)cua * 5 + sl];
            bva = v_bias[(size_t)cva * 5 + sl];
            bub = u_bias[(size_t)cub * 5 + sl];
            bvb = v_bias[(size_t)cvb * 5 + sl];
        }

        // Products in fp16 (v_pk_mul_f16 x4 per round).
        F16x8 Pa, Pb;
        Pa.v = Ua.v * Va.v;
        Pb.v = Ub.v * Vb.v;

        // K=3 partials via dot2 chains (f32 accumulate, no cvt storm).
        float qa0 = 0.f, qa1 = 0.f, qa2 = 0.f;
        float qb0 = 0.f, qb1 = 0.f, qb2 = 0.f;
        #pragma unroll
        for (int j = 0; j < 4; ++j) {
            qa0 = dot2acc(Pa.h[j], wk[0][j], qa0);
            qa1 = dot2acc(Pa.h[j], wk[1][j], qa1);
            qa2 = dot2acc(Pa.h[j], wk[2][j], qa2);
            qb0 = dot2acc(Pb.h[j], wk[0][j], qb0);
            qb1 = dot2acc(Pb.h[j], wk[1][j], qb1);
            qb2 = dot2acc(Pb.h[j], wk[2][j], qb2);
        }

        // 8-lane reductions (3 DPP steps each).
        reduce8_3(qa0, qa1, qa2);
        reduce8_3(qb0, qb1, qb2);

        if (sl < 5) {
            if (cea < E)
                out[(size_t)cea * 5 + sl] = qa0 * s0 + qa1 * s1 + qa2 * s2 + bua + bva;
            if (ceb < E)
                out[(size_t)ceb * 5 + sl] = qb0 * s0 + qb1 * s1 + qb2 * s2 + bub + bvb;
        }
    }
}

// ---------- fallback: direct fp32 (only if ws too small; normally unused) ---
__device__ __forceinline__ void reduce16_3f(float& a, float& b, float& c) {
    a = dpp_add<0xB1>(a);  b = dpp_add<0xB1>(b);  c = dpp_add<0xB1>(c);
    a = dpp_add<0x4E>(a);  b = dpp_add<0x4E>(b);  c = dpp_add<0x4E>(c);
    a = dpp_add<0x124>(a); b = dpp_add<0x124>(b); c = dpp_add<0x124>(c);
    a = dpp_add<0x128>(a); b = dpp_add<0x128>(b); c = dpp_add<0x128>(c);
}

__global__ __launch_bounds__(256) void bilinear_edges_f32(
    const float* __restrict__ u_feat, const float* __restrict__ v_feat,
    const float* __restrict__ W, const float* __restrict__ scalars,
    const float* __restrict__ u_bias, const float* __restrict__ v_bias,
    const int* __restrict__ u_idx, const int* __restrict__ v_idx,
    float* __restrict__ out, int E)
{
    const int tid    = blockIdx.x * blockDim.x + threadIdx.x;
    const int sl     = threadIdx.x & 15;
    const int group  = tid >> 4;
    const int ngroup = (gridDim.x * blockDim.x) >> 4;

    const int d0 = sl * 4;
    float w0[4], w1[4], w2[4];
    #pragma unroll
    for (int t = 0; t < 4; ++t) {
        w0[t] = W[0 * 64 + d0 + t];
        w1[t] = W[1 * 64 + d0 + t];
        w2[t] = W[2 * 64 + d0 + t];
    }
    float s0 = 0.f, s1 = 0.f, s2 = 0.f;
    if (sl < 5) { s0 = scalars[sl]; s1 = scalars[5 + sl]; s2 = scalars[10 + sl]; }

    for (int e = group; e < E; e += ngroup) {
        const int uu = u_idx[e];
        const int vv = v_idx[e];
        const float4 u4 = *reinterpret_cast<const float4*>(u_feat + (size_t)uu * 64 + d0);
        const float4 v4 = *reinterpret_cast<const float4*>(v_feat + (size_t)vv * 64 + d0);
        float ubx = 0.f, vbx = 0.f;
        if (sl < 5) { ubx = u_bias[(size_t)uu * 5 + sl]; vbx = v_bias[(size_t)vv * 5 + sl]; }

        const float p0 = u4.x * v4.x, p1 = u4.y * v4.y,
                    p2 = u4.z * v4.z, p3 = u4.w * v4.w;
        float q0 = p0*w0[0] + p1*w0[1] + p2*w0[2] + p3*w0[3];
        float q1 = p0*w1[0] + p1*w1[1] + p2*w1[2] + p3*w1[3];
        float q2 = p0*w2[0] + p1*w2[1] + p2*w2[2] + p3*w2[3];
        reduce16_3f(q0, q1, q2);
        if (sl < 5)
            out[(size_t)e * 5 + sl] = q0 * s0 + q1 * s1 + q2 * s2 + ubx + vbx;
    }
}

extern "C" void kernel_launch(void* const* d_in, const int* in_sizes, int n_in,
                              void* d_out, int out_size, void* d_ws, size_t ws_size,
                              hipStream_t stream) {
    const float* u_feat  = (const float*)d_in[0];
    const float* v_feat  = (const float*)d_in[1];
    const float* W       = (const float*)d_in[2];
    const float* scalars = (const float*)d_in[3];
    const float* u_bias  = (const float*)d_in[4];
    const float* v_bias  = (const float*)d_in[5];
    const int*   u_idx   = (const int*)d_in[6];
    const int*   v_idx   = (const int*)d_in[7];
    float*       out     = (float*)d_out;

    const int nu = in_sizes[0];          // NUM_USERS * 64
    const int nv = in_sizes[1];          // NUM_ITEMS * 64
    const int E  = in_sizes[6];          // 2,000,000 edges

    const size_t ws_need = (size_t)(nu + nv) * sizeof(__half);

    if (ws_size >= ws_need) {
        __half* u_h = (__half*)d_ws;
        __half* v_h = u_h + nu;
        convert_tables_fp16<<<2048, 256, 0, stream>>>(u_feat, v_feat, u_h, v_h, nu, nv);
        bilinear_dot8<<<2048, 256, 0, stream>>>(
            u_h, v_h, W, scalars, u_bias, v_bias, u_idx, v_idx, out, E);
    } else {
        bilinear_edges_f32<<<2048, 256, 0, stream>>>(
            u_feat, v_feat, W, scalars, u_bias, v_bias, u_idx, v_idx, out, E);
    }
}